// Round 1
// baseline (473.713 us; speedup 1.0000x reference)
//
#include <hip/hip_runtime.h>
#include <math.h>

#define NV 8192
#define CAP 64

// ---------------------------------------------------------------------------
// Kernel A: one pass over adj (256 MB): per-row degree (exact: 0/1 sums in
// f32), ELL column list (off-diagonal nonzeros), diagonal value (adj[i,i]+1).
// One block per row, coalesced float4 reads.
// ---------------------------------------------------------------------------
__global__ __launch_bounds__(256) void build_graph(
    const float* __restrict__ adj, int* __restrict__ cols,
    int* __restrict__ rowcount, float* __restrict__ dinv,
    float* __restrict__ diagv) {
  int row = blockIdx.x;
  int t = threadIdx.x;
  __shared__ int cnt;
  __shared__ float sdiag;
  __shared__ float ssum[256];
  if (t == 0) { cnt = 0; sdiag = 0.0f; }
  __syncthreads();
  const float4* arow = (const float4*)(adj + (size_t)row * NV);
  float s = 0.0f;
  for (int i = t; i < NV / 4; i += 256) {
    float4 v = arow[i];
    s += v.x + v.y + v.z + v.w;
    int c0 = i * 4;
    if (v.x != 0.0f) { if (c0 + 0 == row) sdiag = v.x; else { int p = atomicAdd(&cnt, 1); if (p < CAP) cols[(size_t)row * CAP + p] = c0 + 0; } }
    if (v.y != 0.0f) { if (c0 + 1 == row) sdiag = v.y; else { int p = atomicAdd(&cnt, 1); if (p < CAP) cols[(size_t)row * CAP + p] = c0 + 1; } }
    if (v.z != 0.0f) { if (c0 + 2 == row) sdiag = v.z; else { int p = atomicAdd(&cnt, 1); if (p < CAP) cols[(size_t)row * CAP + p] = c0 + 2; } }
    if (v.w != 0.0f) { if (c0 + 3 == row) sdiag = v.w; else { int p = atomicAdd(&cnt, 1); if (p < CAP) cols[(size_t)row * CAP + p] = c0 + 3; } }
  }
  ssum[t] = s;
  __syncthreads();
  for (int off = 128; off > 0; off >>= 1) {
    if (t < off) ssum[t] += ssum[t + off];
    __syncthreads();
  }
  if (t == 0) {
    float deg = ssum[0] + 1.0f;         // +1 from the identity (self loop)
    dinv[row] = 1.0f / sqrtf(deg);
    diagv[row] = sdiag + 1.0f;          // A_hat diagonal value
    rowcount[row] = cnt > CAP ? CAP : cnt;
  }
}

// ---------------------------------------------------------------------------
// Kernel B/D: f32 GEMM, C[M x ldc] = A[M x K] @ B[K x Nvalid], 64x64 tile,
// 256 threads, 4x4 micro-tile. Columns >= Nvalid are computed as zeros
// (used to pad layer-2's N=40 up to one 64-wide tile).
// As stride 68 breaks the 4-way write conflict (bank = (16a+4j+r)%32 -> 2-way).
// ---------------------------------------------------------------------------
__global__ __launch_bounds__(256) void gemm_f32(
    const float* __restrict__ A, const float* __restrict__ B,
    float* __restrict__ C, int M, int K, int Nvalid, int ldb, int ldc) {
  __shared__ float As[16][68];
  __shared__ float Bs[16][64];
  int t = threadIdx.x;
  int bm0 = blockIdx.y * 64;
  int bn0 = blockIdx.x * 64;
  int tx = t & 15, ty = t >> 4;
  int ar = t >> 2;          // 0..63 : A row within tile
  int ak = (t & 3) * 4;     // 0,4,8,12 : A k-offset (float4)
  int bk = t >> 4;          // 0..15 : B k within tile
  int bn = (t & 15) * 4;    // 0..60 : B col within tile (float4)
  float acc[4][4] = {};
  for (int k0 = 0; k0 < K; k0 += 16) {
    float4 av = *(const float4*)(A + (size_t)(bm0 + ar) * K + k0 + ak);
    float4 bv;
    int bc = bn0 + bn;
    if (bc + 3 < Nvalid) {
      bv = *(const float4*)(B + (size_t)(k0 + bk) * ldb + bc);
    } else {
      bv.x = (bc + 0 < Nvalid) ? B[(size_t)(k0 + bk) * ldb + bc + 0] : 0.0f;
      bv.y = (bc + 1 < Nvalid) ? B[(size_t)(k0 + bk) * ldb + bc + 1] : 0.0f;
      bv.z = (bc + 2 < Nvalid) ? B[(size_t)(k0 + bk) * ldb + bc + 2] : 0.0f;
      bv.w = (bc + 3 < Nvalid) ? B[(size_t)(k0 + bk) * ldb + bc + 3] : 0.0f;
    }
    As[ak + 0][ar] = av.x;
    As[ak + 1][ar] = av.y;
    As[ak + 2][ar] = av.z;
    As[ak + 3][ar] = av.w;
    *(float4*)(&Bs[bk][bn]) = bv;
    __syncthreads();
#pragma unroll
    for (int kk = 0; kk < 16; kk++) {
      float4 a = *(const float4*)(&As[kk][ty * 4]);
      float4 b = *(const float4*)(&Bs[kk][tx * 4]);
      acc[0][0] += a.x * b.x; acc[0][1] += a.x * b.y; acc[0][2] += a.x * b.z; acc[0][3] += a.x * b.w;
      acc[1][0] += a.y * b.x; acc[1][1] += a.y * b.y; acc[1][2] += a.y * b.z; acc[1][3] += a.y * b.w;
      acc[2][0] += a.z * b.x; acc[2][1] += a.z * b.y; acc[2][2] += a.z * b.z; acc[2][3] += a.z * b.w;
      acc[3][0] += a.w * b.x; acc[3][1] += a.w * b.y; acc[3][2] += a.w * b.z; acc[3][3] += a.w * b.w;
    }
    __syncthreads();
  }
#pragma unroll
  for (int i = 0; i < 4; i++) {
    *(float4*)(C + (size_t)(bm0 + ty * 4 + i) * ldc + bn0 + tx * 4) =
        make_float4(acc[i][0], acc[i][1], acc[i][2], acc[i][3]);
  }
}

// ---------------------------------------------------------------------------
// Kernel C: H[i,:] = relu(dinv_i * (sum_{c in nbr(i)} dinv_c * Z[c,:]
//                                   + diag_i * dinv_i * Z[i,:]))
// Block per row (256 threads = 256 features), coalesced gathers (L2-resident).
// ---------------------------------------------------------------------------
__global__ __launch_bounds__(256) void spmm_relu_k(
    const float* __restrict__ Z, const int* __restrict__ cols,
    const int* __restrict__ rowcount, const float* __restrict__ dinv,
    const float* __restrict__ diagv, float* __restrict__ H) {
  int row = blockIdx.x;
  int f = threadIdx.x;
  float di = dinv[row];
  float acc = diagv[row] * di * Z[(size_t)row * 256 + f];
  int cnt = rowcount[row];
  const int* cr = cols + (size_t)row * CAP;
  for (int e = 0; e < cnt; e++) {
    int c = cr[e];
    acc += dinv[c] * Z[(size_t)c * 256 + f];
  }
  H[(size_t)row * 256 + f] = fmaxf(acc * di, 0.0f);
}

// ---------------------------------------------------------------------------
// Kernel E: layer-2 sparse aggregate + relu + log_softmax, fused.
// One wave (64 lanes) per row; 40 active lanes; shuffle reductions.
// Z is the padded [8192 x 64] HW2 buffer.
// ---------------------------------------------------------------------------
__global__ __launch_bounds__(256) void spmm2_lsm_k(
    const float* __restrict__ Z, const int* __restrict__ cols,
    const int* __restrict__ rowcount, const float* __restrict__ dinv,
    const float* __restrict__ diagv, float* __restrict__ out) {
  int lane = threadIdx.x & 63;
  int row = blockIdx.x * 4 + (threadIdx.x >> 6);
  float di = dinv[row];
  float acc = 0.0f;
  if (lane < 40) acc = diagv[row] * di * Z[(size_t)row * 64 + lane];
  int cnt = rowcount[row];
  const int* cr = cols + (size_t)row * CAP;
  for (int e = 0; e < cnt; e++) {
    int c = cr[e];
    if (lane < 40) acc += dinv[c] * Z[(size_t)c * 64 + lane];
  }
  float h2 = (lane < 40) ? fmaxf(acc * di, 0.0f) : -INFINITY;
  float m = h2;
  for (int off = 32; off > 0; off >>= 1) m = fmaxf(m, __shfl_xor(m, off, 64));
  float ex = (lane < 40) ? expf(h2 - m) : 0.0f;
  float s = ex;
  for (int off = 32; off > 0; off >>= 1) s += __shfl_xor(s, off, 64);
  float ls = logf(s);
  if (lane < 40) out[(size_t)row * 40 + lane] = h2 - m - ls;
}

// ---------------------------------------------------------------------------
// Workspace layout (bytes):
//   cols     @ 0        : 8192*64*4 = 2097152
//   rowcount @ 2097152  : 32768
//   dinv     @ 2130048? -> see offsets below (all 16B aligned)
//   XW1      : 8192*256*4 = 8388608
//   H        : 8388608
//   HW2(pad) : 8192*64*4 = 2097152
// Total ~20.1 MB.
// ---------------------------------------------------------------------------
extern "C" void kernel_launch(void* const* d_in, const int* in_sizes, int n_in,
                              void* d_out, int out_size, void* d_ws, size_t ws_size,
                              hipStream_t stream) {
  (void)in_sizes; (void)n_in; (void)out_size; (void)ws_size;
  const float* x   = (const float*)d_in[0];
  const float* adj = (const float*)d_in[1];
  const float* W1  = (const float*)d_in[2];
  const float* W2  = (const float*)d_in[3];
  float* out = (float*)d_out;
  char* ws = (char*)d_ws;

  int*   cols     = (int*)(ws);
  int*   rowcount = (int*)(ws + 2097152);
  float* dinv     = (float*)(ws + 2097152 + 32768);
  float* diagv    = (float*)(ws + 2097152 + 65536);
  float* XW1      = (float*)(ws + 2097152 + 98304);
  float* H        = (float*)(ws + 2097152 + 98304 + 8388608);
  float* HW2      = (float*)(ws + 2097152 + 98304 + 16777216);

  hipLaunchKernelGGL(build_graph, dim3(NV), dim3(256), 0, stream,
                     adj, cols, rowcount, dinv, diagv);
  hipLaunchKernelGGL(gemm_f32, dim3(4, 128), dim3(256), 0, stream,
                     x, W1, XW1, NV, 512, 256, 256, 256);
  hipLaunchKernelGGL(spmm_relu_k, dim3(NV), dim3(256), 0, stream,
                     XW1, cols, rowcount, dinv, diagv, H);
  hipLaunchKernelGGL(gemm_f32, dim3(1, 128), dim3(256), 0, stream,
                     H, W2, HW2, NV, 256, 40, 40, 64);
  hipLaunchKernelGGL(spmm2_lsm_k, dim3(NV / 4), dim3(256), 0, stream,
                     HW2, cols, rowcount, dinv, diagv, out);
}

// Round 2
// 451.404 us; speedup vs baseline: 1.0494x; 1.0494x over previous
//
#include <hip/hip_runtime.h>
#include <math.h>

#define NV 8192
#define CAP 64

// ---------------------------------------------------------------------------
// Kernel A: one pass over adj (256 MB): ballot-compacted ELL extraction,
// popcount degree (entries are exactly 0.0/1.0), diag flag.
// One block (4 waves) per row, coalesced float4 reads. BW floor ~42 us.
// ---------------------------------------------------------------------------
__global__ __launch_bounds__(256) void build_graph(
    const float* __restrict__ adj, int* __restrict__ cols,
    int* __restrict__ rowcount, float* __restrict__ dinv,
    float* __restrict__ diagv) {
  int row = blockIdx.x;
  int t = threadIdx.x;
  int lane = t & 63;
  __shared__ int cnt;
  __shared__ int diag_nz;
  __shared__ int wsum[4];
  if (t == 0) { cnt = 0; diag_nz = 0; }
  __syncthreads();
  const float4* arow = (const float4*)(adj + (size_t)row * NV);
  int mycount = 0;
  for (int i = t; i < NV / 4; i += 256) {
    float4 v = arow[i];
    float va[4] = {v.x, v.y, v.z, v.w};
#pragma unroll
    for (int j = 0; j < 4; j++) {
      bool nz = (va[j] != 0.0f);
      mycount += nz ? 1 : 0;
      int c = i * 4 + j;
      bool isdiag = nz && (c == row);
      bool take = nz && !isdiag;
      if (isdiag) diag_nz = 1;  // at most one writer per block
      unsigned long long m = __ballot(take);
      if (m != 0ull) {  // wave-uniform skip (~88% of stripes empty)
        int tot = __popcll(m);
        int pre = __popcll(m & ((1ull << lane) - 1ull));
        int leader = __ffsll((unsigned long long)m) - 1;
        int base = 0;
        if (lane == leader) base = atomicAdd(&cnt, tot);
        base = __shfl(base, leader, 64);
        if (take) {
          int p = base + pre;
          if (p < CAP) cols[(size_t)row * CAP + p] = c;
        }
      }
    }
  }
  for (int off = 32; off > 0; off >>= 1) mycount += __shfl_xor(mycount, off, 64);
  if (lane == 0) wsum[t >> 6] = mycount;
  __syncthreads();
  if (t == 0) {
    int nnz = wsum[0] + wsum[1] + wsum[2] + wsum[3];  // includes diagonal if present
    float deg = (float)nnz + 1.0f;                    // +1 from identity
    dinv[row] = 1.0f / sqrtf(deg);
    diagv[row] = diag_nz ? 2.0f : 1.0f;               // adj[i,i] + 1
    rowcount[row] = cnt > CAP ? CAP : cnt;
  }
}

// ---------------------------------------------------------------------------
// Kernel B/D: f32 GEMM, C[M x ldc] = A[M x K] @ B[K x Nvalid], 64x64 tile,
// 256 threads, 4x4 micro-tile. Columns >= Nvalid computed as zeros (pads
// layer-2's N=40 to a 64-wide tile). As stride 68 keeps stores conflict-free.
// LDS-bound ~78 TF -> ~27 us for layer 1.
// ---------------------------------------------------------------------------
__global__ __launch_bounds__(256) void gemm_f32(
    const float* __restrict__ A, const float* __restrict__ B,
    float* __restrict__ C, int M, int K, int Nvalid, int ldb, int ldc) {
  __shared__ float As[16][68];
  __shared__ float Bs[16][64];
  int t = threadIdx.x;
  int bm0 = blockIdx.y * 64;
  int bn0 = blockIdx.x * 64;
  int tx = t & 15, ty = t >> 4;
  int ar = t >> 2;
  int ak = (t & 3) * 4;
  int bk = t >> 4;
  int bn = (t & 15) * 4;
  float acc[4][4] = {};
  for (int k0 = 0; k0 < K; k0 += 16) {
    float4 av = *(const float4*)(A + (size_t)(bm0 + ar) * K + k0 + ak);
    float4 bv;
    int bc = bn0 + bn;
    if (bc + 3 < Nvalid) {
      bv = *(const float4*)(B + (size_t)(k0 + bk) * ldb + bc);
    } else {
      bv.x = (bc + 0 < Nvalid) ? B[(size_t)(k0 + bk) * ldb + bc + 0] : 0.0f;
      bv.y = (bc + 1 < Nvalid) ? B[(size_t)(k0 + bk) * ldb + bc + 1] : 0.0f;
      bv.z = (bc + 2 < Nvalid) ? B[(size_t)(k0 + bk) * ldb + bc + 2] : 0.0f;
      bv.w = (bc + 3 < Nvalid) ? B[(size_t)(k0 + bk) * ldb + bc + 3] : 0.0f;
    }
    As[ak + 0][ar] = av.x;
    As[ak + 1][ar] = av.y;
    As[ak + 2][ar] = av.z;
    As[ak + 3][ar] = av.w;
    *(float4*)(&Bs[bk][bn]) = bv;
    __syncthreads();
#pragma unroll
    for (int kk = 0; kk < 16; kk++) {
      float4 a = *(const float4*)(&As[kk][ty * 4]);
      float4 b = *(const float4*)(&Bs[kk][tx * 4]);
      acc[0][0] += a.x * b.x; acc[0][1] += a.x * b.y; acc[0][2] += a.x * b.z; acc[0][3] += a.x * b.w;
      acc[1][0] += a.y * b.x; acc[1][1] += a.y * b.y; acc[1][2] += a.y * b.z; acc[1][3] += a.y * b.w;
      acc[2][0] += a.z * b.x; acc[2][1] += a.z * b.y; acc[2][2] += a.z * b.z; acc[2][3] += a.z * b.w;
      acc[3][0] += a.w * b.x; acc[3][1] += a.w * b.y; acc[3][2] += a.w * b.z; acc[3][3] += a.w * b.w;
    }
    __syncthreads();
  }
#pragma unroll
  for (int i = 0; i < 4; i++) {
    *(float4*)(C + (size_t)(bm0 + ty * 4 + i) * ldc + bn0 + tx * 4) =
        make_float4(acc[i][0], acc[i][1], acc[i][2], acc[i][3]);
  }
}

// ---------------------------------------------------------------------------
// Kernel C: layer-1 aggregate + relu. One WAVE per row, float4 per lane:
// one 1 KB memory instruction per gathered row; unroll x4 -> 4 independent
// gathers in flight (kills the serial latency chain of round 1).
// ---------------------------------------------------------------------------
__global__ __launch_bounds__(256) void spmm_relu_k(
    const float* __restrict__ Z, const int* __restrict__ cols,
    const int* __restrict__ rowcount, const float* __restrict__ dinv,
    const float* __restrict__ diagv, float* __restrict__ H) {
  int lane = threadIdx.x & 63;
  int row = blockIdx.x * 4 + (threadIdx.x >> 6);
  const float4* Zr = (const float4*)Z;  // [NV][64] float4 view of [NV][256]
  float di = dinv[row];
  float4 z = Zr[(size_t)row * 64 + lane];
  float dd = diagv[row] * di;
  float4 acc;
  acc.x = dd * z.x; acc.y = dd * z.y; acc.z = dd * z.z; acc.w = dd * z.w;
  int cnt = rowcount[row];
  const int* cr = cols + (size_t)row * CAP;
  int e = 0;
  for (; e + 4 <= cnt; e += 4) {
    int c0 = cr[e + 0], c1 = cr[e + 1], c2 = cr[e + 2], c3 = cr[e + 3];
    float w0 = dinv[c0], w1 = dinv[c1], w2 = dinv[c2], w3 = dinv[c3];
    float4 g0 = Zr[(size_t)c0 * 64 + lane];
    float4 g1 = Zr[(size_t)c1 * 64 + lane];
    float4 g2 = Zr[(size_t)c2 * 64 + lane];
    float4 g3 = Zr[(size_t)c3 * 64 + lane];
    acc.x += w0 * g0.x + w1 * g1.x + w2 * g2.x + w3 * g3.x;
    acc.y += w0 * g0.y + w1 * g1.y + w2 * g2.y + w3 * g3.y;
    acc.z += w0 * g0.z + w1 * g1.z + w2 * g2.z + w3 * g3.z;
    acc.w += w0 * g0.w + w1 * g1.w + w2 * g2.w + w3 * g3.w;
  }
  for (; e < cnt; e++) {
    int c = cr[e];
    float w = dinv[c];
    float4 g = Zr[(size_t)c * 64 + lane];
    acc.x += w * g.x; acc.y += w * g.y; acc.z += w * g.z; acc.w += w * g.w;
  }
  float4 o;
  o.x = fmaxf(acc.x * di, 0.0f);
  o.y = fmaxf(acc.y * di, 0.0f);
  o.z = fmaxf(acc.z * di, 0.0f);
  o.w = fmaxf(acc.w * di, 0.0f);
  ((float4*)H)[(size_t)row * 64 + lane] = o;
}

// ---------------------------------------------------------------------------
// Kernel E: layer-2 aggregate + relu + log_softmax. One wave per row over the
// 64-wide padded HW2 (cols 40..63 are exact zeros, so no lane guard needed in
// the gather loop); unroll x4 for MLP; shuffle reductions for max/sum.
// ---------------------------------------------------------------------------
__global__ __launch_bounds__(256) void spmm2_lsm_k(
    const float* __restrict__ Z, const int* __restrict__ cols,
    const int* __restrict__ rowcount, const float* __restrict__ dinv,
    const float* __restrict__ diagv, float* __restrict__ out) {
  int lane = threadIdx.x & 63;
  int row = blockIdx.x * 4 + (threadIdx.x >> 6);
  float di = dinv[row];
  float acc = diagv[row] * di * Z[(size_t)row * 64 + lane];
  int cnt = rowcount[row];
  const int* cr = cols + (size_t)row * CAP;
  int e = 0;
  for (; e + 4 <= cnt; e += 4) {
    int c0 = cr[e + 0], c1 = cr[e + 1], c2 = cr[e + 2], c3 = cr[e + 3];
    float w0 = dinv[c0], w1 = dinv[c1], w2 = dinv[c2], w3 = dinv[c3];
    float g0 = Z[(size_t)c0 * 64 + lane];
    float g1 = Z[(size_t)c1 * 64 + lane];
    float g2 = Z[(size_t)c2 * 64 + lane];
    float g3 = Z[(size_t)c3 * 64 + lane];
    acc += w0 * g0 + w1 * g1 + w2 * g2 + w3 * g3;
  }
  for (; e < cnt; e++) {
    int c = cr[e];
    acc += dinv[c] * Z[(size_t)c * 64 + lane];
  }
  float h2 = (lane < 40) ? fmaxf(acc * di, 0.0f) : -INFINITY;
  float m = h2;
  for (int off = 32; off > 0; off >>= 1) m = fmaxf(m, __shfl_xor(m, off, 64));
  float ex = (lane < 40) ? expf(h2 - m) : 0.0f;
  float s = ex;
  for (int off = 32; off > 0; off >>= 1) s += __shfl_xor(s, off, 64);
  float ls = logf(s);
  if (lane < 40) out[(size_t)row * 40 + lane] = h2 - m - ls;
}

// ---------------------------------------------------------------------------
// Workspace layout (bytes, all 16B-aligned):
//   cols     @ 0         : 2097152
//   rowcount @ 2097152   : 32768
//   dinv     @ 2129920   : 32768
//   diagv    @ 2162688   : 32768
//   XW1      @ 2195456   : 8388608
//   H        @ 10584064  : 8388608
//   HW2(pad) @ 18972672  : 2097152   (8192 x 64, cols 40..63 zero)
// ---------------------------------------------------------------------------
extern "C" void kernel_launch(void* const* d_in, const int* in_sizes, int n_in,
                              void* d_out, int out_size, void* d_ws, size_t ws_size,
                              hipStream_t stream) {
  (void)in_sizes; (void)n_in; (void)out_size; (void)ws_size;
  const float* x   = (const float*)d_in[0];
  const float* adj = (const float*)d_in[1];
  const float* W1  = (const float*)d_in[2];
  const float* W2  = (const float*)d_in[3];
  float* out = (float*)d_out;
  char* ws = (char*)d_ws;

  int*   cols     = (int*)(ws);
  int*   rowcount = (int*)(ws + 2097152);
  float* dinv     = (float*)(ws + 2129920);
  float* diagv    = (float*)(ws + 2162688);
  float* XW1      = (float*)(ws + 2195456);
  float* H        = (float*)(ws + 10584064);
  float* HW2      = (float*)(ws + 18972672);

  hipLaunchKernelGGL(build_graph, dim3(NV), dim3(256), 0, stream,
                     adj, cols, rowcount, dinv, diagv);
  hipLaunchKernelGGL(gemm_f32, dim3(4, 128), dim3(256), 0, stream,
                     x, W1, XW1, NV, 512, 256, 256, 256);
  hipLaunchKernelGGL(spmm_relu_k, dim3(NV / 4), dim3(256), 0, stream,
                     XW1, cols, rowcount, dinv, diagv, H);
  hipLaunchKernelGGL(gemm_f32, dim3(1, 128), dim3(256), 0, stream,
                     H, W2, HW2, NV, 256, 40, 40, 64);
  hipLaunchKernelGGL(spmm2_lsm_k, dim3(NV / 4), dim3(256), 0, stream,
                     HW2, cols, rowcount, dinv, diagv, out);
}

// Round 3
// 437.863 us; speedup vs baseline: 1.0819x; 1.0309x over previous
//
#include <hip/hip_runtime.h>
#include <math.h>

#define NV 8192
#define CAP 64

typedef __attribute__((ext_vector_type(8))) short short8;
typedef __attribute__((ext_vector_type(4))) float f32x4;

static __device__ __forceinline__ unsigned short f2bf(float v) {
  unsigned int u = __float_as_uint(v);
  unsigned int r = (u + 0x7fffu + ((u >> 16) & 1u)) >> 16;  // RNE
  return (unsigned short)r;
}
static __device__ __forceinline__ float bf2f(unsigned short h) {
  return __uint_as_float(((unsigned int)h) << 16);
}

// ---------------------------------------------------------------------------
// Kernel A: one pass over adj (256 MB): ballot-compacted ELL extraction,
// popcount degree, diag flag. BW floor ~42 us.
// ---------------------------------------------------------------------------
__global__ __launch_bounds__(256) void build_graph(
    const float* __restrict__ adj, int* __restrict__ cols,
    int* __restrict__ rowcount, float* __restrict__ dinv,
    float* __restrict__ diagv) {
  int row = blockIdx.x;
  int t = threadIdx.x;
  int lane = t & 63;
  __shared__ int cnt;
  __shared__ int diag_nz;
  __shared__ int wsum[4];
  if (t == 0) { cnt = 0; diag_nz = 0; }
  __syncthreads();
  const float4* arow = (const float4*)(adj + (size_t)row * NV);
  int mycount = 0;
  for (int i = t; i < NV / 4; i += 256) {
    float4 v = arow[i];
    float va[4] = {v.x, v.y, v.z, v.w};
#pragma unroll
    for (int j = 0; j < 4; j++) {
      bool nz = (va[j] != 0.0f);
      mycount += nz ? 1 : 0;
      int c = i * 4 + j;
      bool isdiag = nz && (c == row);
      bool take = nz && !isdiag;
      if (isdiag) diag_nz = 1;
      unsigned long long m = __ballot(take);
      if (m != 0ull) {
        int tot = __popcll(m);
        int pre = __popcll(m & ((1ull << lane) - 1ull));
        int leader = __ffsll((unsigned long long)m) - 1;
        int base = 0;
        if (lane == leader) base = atomicAdd(&cnt, tot);
        base = __shfl(base, leader, 64);
        if (take) {
          int p = base + pre;
          if (p < CAP) cols[(size_t)row * CAP + p] = c;
        }
      }
    }
  }
  for (int off = 32; off > 0; off >>= 1) mycount += __shfl_xor(mycount, off, 64);
  if (lane == 0) wsum[t >> 6] = mycount;
  __syncthreads();
  if (t == 0) {
    int nnz = wsum[0] + wsum[1] + wsum[2] + wsum[3];
    float deg = (float)nnz + 1.0f;
    dinv[row] = 1.0f / sqrtf(deg);
    diagv[row] = diag_nz ? 2.0f : 1.0f;
    rowcount[row] = cnt > CAP ? CAP : cnt;
  }
}

// ---------------------------------------------------------------------------
// Prep 1: split x [8192x512] f32 into bf16 hi + lo (x = hi + lo + O(2^-18)).
// ---------------------------------------------------------------------------
__global__ __launch_bounds__(256) void split_a(
    const float* __restrict__ x, unsigned short* __restrict__ Ah,
    unsigned short* __restrict__ Al) {
  int i = blockIdx.x * 256 + threadIdx.x;  // over float4 groups; n = 1048576
  float4 v = ((const float4*)x)[i];
  ushort4 h, l;
  h.x = f2bf(v.x); l.x = f2bf(v.x - bf2f(h.x));
  h.y = f2bf(v.y); l.y = f2bf(v.y - bf2f(h.y));
  h.z = f2bf(v.z); l.z = f2bf(v.z - bf2f(h.z));
  h.w = f2bf(v.w); l.w = f2bf(v.w - bf2f(h.w));
  ((ushort4*)Ah)[i] = h;
  ((ushort4*)Al)[i] = l;
}

// ---------------------------------------------------------------------------
// Prep 2: W1 [512][256] f32 -> transposed bf16 hi/lo [N=256][K=512].
// grid (256, 2) x 256 threads: n = blockIdx.x, k = blockIdx.y*256 + tid.
// ---------------------------------------------------------------------------
__global__ __launch_bounds__(256) void split_w1t(
    const float* __restrict__ W1, unsigned short* __restrict__ Bh,
    unsigned short* __restrict__ Bl) {
  int n = blockIdx.x;
  int k = blockIdx.y * 256 + threadIdx.x;
  float v = W1[(size_t)k * 256 + n];
  unsigned short h = f2bf(v);
  Bh[(size_t)n * 512 + k] = h;
  Bl[(size_t)n * 512 + k] = f2bf(v - bf2f(h));
}

// ---------------------------------------------------------------------------
// Kernel B: XW1[8192][256] = x @ W1 via split-bf16 MFMA (hi*hi + lo*hi + hi*lo).
// Tile 128(M) x 64(N), K-step 32, 4 waves; wave w covers rows [w*32, w*32+32).
// A-frag: lane holds A[m=lane&15][k=quad*8+j]; B-frag from Bt[n=lane&15][k];
// C/D: row = quad*4+reg, col = lane&15 (m89-verified layouts).
// LDS rows padded to 40 ushorts (80 B: 16B-aligned, 2-way-max bank conflicts).
// Grid (4, 64) n-fastest so same-bm blocks co-run -> A-tile L2 reuse.
// ---------------------------------------------------------------------------
__global__ __launch_bounds__(256) void gemm1_mfma(
    const unsigned short* __restrict__ Ah, const unsigned short* __restrict__ Al,
    const unsigned short* __restrict__ Bh, const unsigned short* __restrict__ Bl,
    float* __restrict__ C) {
  const int K = 512;
  __shared__ __align__(16) unsigned short sAh[128][40];
  __shared__ __align__(16) unsigned short sAl[128][40];
  __shared__ __align__(16) unsigned short sBh[64][40];
  __shared__ __align__(16) unsigned short sBl[64][40];
  int t = threadIdx.x;
  int bn = blockIdx.x * 64;
  int bm = blockIdx.y * 128;
  int lane = t & 63, w = t >> 6;
  int quad = lane >> 4, m16 = lane & 15;
  f32x4 acc[2][4] = {};
  for (int k0 = 0; k0 < K; k0 += 32) {
#pragma unroll
    for (int i = 0; i < 2; i++) {  // A tile: 128 rows x 32 k
      int id = t + i * 256;
      int row = id >> 2, q = id & 3;
      *(uint4*)&sAh[row][q * 8] = *(const uint4*)&Ah[(size_t)(bm + row) * K + k0 + q * 8];
      *(uint4*)&sAl[row][q * 8] = *(const uint4*)&Al[(size_t)(bm + row) * K + k0 + q * 8];
    }
    {  // B tile: 64 n x 32 k
      int row = t >> 2, q = t & 3;
      *(uint4*)&sBh[row][q * 8] = *(const uint4*)&Bh[(size_t)(bn + row) * K + k0 + q * 8];
      *(uint4*)&sBl[row][q * 8] = *(const uint4*)&Bl[(size_t)(bn + row) * K + k0 + q * 8];
    }
    __syncthreads();
    short8 ah[2], al[2], bh[4], bl[4];
#pragma unroll
    for (int i = 0; i < 2; i++) {
      ah[i] = *(const short8*)&sAh[w * 32 + i * 16 + m16][quad * 8];
      al[i] = *(const short8*)&sAl[w * 32 + i * 16 + m16][quad * 8];
    }
#pragma unroll
    for (int j = 0; j < 4; j++) {
      bh[j] = *(const short8*)&sBh[j * 16 + m16][quad * 8];
      bl[j] = *(const short8*)&sBl[j * 16 + m16][quad * 8];
    }
#pragma unroll
    for (int i = 0; i < 2; i++)
#pragma unroll
      for (int j = 0; j < 4; j++) {
        acc[i][j] = __builtin_amdgcn_mfma_f32_16x16x32_bf16(ah[i], bh[j], acc[i][j], 0, 0, 0);
        acc[i][j] = __builtin_amdgcn_mfma_f32_16x16x32_bf16(al[i], bh[j], acc[i][j], 0, 0, 0);
        acc[i][j] = __builtin_amdgcn_mfma_f32_16x16x32_bf16(ah[i], bl[j], acc[i][j], 0, 0, 0);
      }
    __syncthreads();
  }
#pragma unroll
  for (int i = 0; i < 2; i++)
#pragma unroll
    for (int j = 0; j < 4; j++)
#pragma unroll
      for (int r = 0; r < 4; r++)
        C[(size_t)(bm + w * 32 + i * 16 + quad * 4 + r) * 256 + bn + j * 16 + m16] =
            acc[i][j][r];
}

// ---------------------------------------------------------------------------
// Kernel D: f32 GEMM for layer 2 (167 MFLOP): C = A[M x K] @ B[K x Nvalid],
// 64x64 tile, 4x4 micro-tile; cols >= Nvalid zero-padded (N=40 -> 64).
// ---------------------------------------------------------------------------
__global__ __launch_bounds__(256) void gemm_f32(
    const float* __restrict__ A, const float* __restrict__ B,
    float* __restrict__ C, int M, int K, int Nvalid, int ldb, int ldc) {
  __shared__ float As[16][68];
  __shared__ float Bs[16][64];
  int t = threadIdx.x;
  int bm0 = blockIdx.y * 64;
  int bn0 = blockIdx.x * 64;
  int tx = t & 15, ty = t >> 4;
  int ar = t >> 2;
  int ak = (t & 3) * 4;
  int bk = t >> 4;
  int bn = (t & 15) * 4;
  float acc[4][4] = {};
  for (int k0 = 0; k0 < K; k0 += 16) {
    float4 av = *(const float4*)(A + (size_t)(bm0 + ar) * K + k0 + ak);
    float4 bv;
    int bc = bn0 + bn;
    if (bc + 3 < Nvalid) {
      bv = *(const float4*)(B + (size_t)(k0 + bk) * ldb + bc);
    } else {
      bv.x = (bc + 0 < Nvalid) ? B[(size_t)(k0 + bk) * ldb + bc + 0] : 0.0f;
      bv.y = (bc + 1 < Nvalid) ? B[(size_t)(k0 + bk) * ldb + bc + 1] : 0.0f;
      bv.z = (bc + 2 < Nvalid) ? B[(size_t)(k0 + bk) * ldb + bc + 2] : 0.0f;
      bv.w = (bc + 3 < Nvalid) ? B[(size_t)(k0 + bk) * ldb + bc + 3] : 0.0f;
    }
    As[ak + 0][ar] = av.x;
    As[ak + 1][ar] = av.y;
    As[ak + 2][ar] = av.z;
    As[ak + 3][ar] = av.w;
    *(float4*)(&Bs[bk][bn]) = bv;
    __syncthreads();
#pragma unroll
    for (int kk = 0; kk < 16; kk++) {
      float4 a = *(const float4*)(&As[kk][ty * 4]);
      float4 b = *(const float4*)(&Bs[kk][tx * 4]);
      acc[0][0] += a.x * b.x; acc[0][1] += a.x * b.y; acc[0][2] += a.x * b.z; acc[0][3] += a.x * b.w;
      acc[1][0] += a.y * b.x; acc[1][1] += a.y * b.y; acc[1][2] += a.y * b.z; acc[1][3] += a.y * b.w;
      acc[2][0] += a.z * b.x; acc[2][1] += a.z * b.y; acc[2][2] += a.z * b.z; acc[2][3] += a.z * b.w;
      acc[3][0] += a.w * b.x; acc[3][1] += a.w * b.y; acc[3][2] += a.w * b.z; acc[3][3] += a.w * b.w;
    }
    __syncthreads();
  }
#pragma unroll
  for (int i = 0; i < 4; i++) {
    *(float4*)(C + (size_t)(bm0 + ty * 4 + i) * ldc + bn0 + tx * 4) =
        make_float4(acc[i][0], acc[i][1], acc[i][2], acc[i][3]);
  }
}

// ---------------------------------------------------------------------------
// Kernel C: layer-1 aggregate + relu. One WAVE per row, float4 per lane,
// unroll x4 -> 4 independent 1 KB gathers in flight.
// ---------------------------------------------------------------------------
__global__ __launch_bounds__(256) void spmm_relu_k(
    const float* __restrict__ Z, const int* __restrict__ cols,
    const int* __restrict__ rowcount, const float* __restrict__ dinv,
    const float* __restrict__ diagv, float* __restrict__ H) {
  int lane = threadIdx.x & 63;
  int row = blockIdx.x * 4 + (threadIdx.x >> 6);
  const float4* Zr = (const float4*)Z;
  float di = dinv[row];
  float4 z = Zr[(size_t)row * 64 + lane];
  float dd = diagv[row] * di;
  float4 acc;
  acc.x = dd * z.x; acc.y = dd * z.y; acc.z = dd * z.z; acc.w = dd * z.w;
  int cnt = rowcount[row];
  const int* cr = cols + (size_t)row * CAP;
  int e = 0;
  for (; e + 4 <= cnt; e += 4) {
    int c0 = cr[e + 0], c1 = cr[e + 1], c2 = cr[e + 2], c3 = cr[e + 3];
    float w0 = dinv[c0], w1 = dinv[c1], w2 = dinv[c2], w3 = dinv[c3];
    float4 g0 = Zr[(size_t)c0 * 64 + lane];
    float4 g1 = Zr[(size_t)c1 * 64 + lane];
    float4 g2 = Zr[(size_t)c2 * 64 + lane];
    float4 g3 = Zr[(size_t)c3 * 64 + lane];
    acc.x += w0 * g0.x + w1 * g1.x + w2 * g2.x + w3 * g3.x;
    acc.y += w0 * g0.y + w1 * g1.y + w2 * g2.y + w3 * g3.y;
    acc.z += w0 * g0.z + w1 * g1.z + w2 * g2.z + w3 * g3.z;
    acc.w += w0 * g0.w + w1 * g1.w + w2 * g2.w + w3 * g3.w;
  }
  for (; e < cnt; e++) {
    int c = cr[e];
    float w = dinv[c];
    float4 g = Zr[(size_t)c * 64 + lane];
    acc.x += w * g.x; acc.y += w * g.y; acc.z += w * g.z; acc.w += w * g.w;
  }
  float4 o;
  o.x = fmaxf(acc.x * di, 0.0f);
  o.y = fmaxf(acc.y * di, 0.0f);
  o.z = fmaxf(acc.z * di, 0.0f);
  o.w = fmaxf(acc.w * di, 0.0f);
  ((float4*)H)[(size_t)row * 64 + lane] = o;
}

// ---------------------------------------------------------------------------
// Kernel E: layer-2 aggregate + relu + log_softmax (wave per row, 64-wide
// padded HW2; cols 40..63 exact zeros).
// ---------------------------------------------------------------------------
__global__ __launch_bounds__(256) void spmm2_lsm_k(
    const float* __restrict__ Z, const int* __restrict__ cols,
    const int* __restrict__ rowcount, const float* __restrict__ dinv,
    const float* __restrict__ diagv, float* __restrict__ out) {
  int lane = threadIdx.x & 63;
  int row = blockIdx.x * 4 + (threadIdx.x >> 6);
  float di = dinv[row];
  float acc = diagv[row] * di * Z[(size_t)row * 64 + lane];
  int cnt = rowcount[row];
  const int* cr = cols + (size_t)row * CAP;
  int e = 0;
  for (; e + 4 <= cnt; e += 4) {
    int c0 = cr[e + 0], c1 = cr[e + 1], c2 = cr[e + 2], c3 = cr[e + 3];
    float w0 = dinv[c0], w1 = dinv[c1], w2 = dinv[c2], w3 = dinv[c3];
    acc += w0 * Z[(size_t)c0 * 64 + lane] + w1 * Z[(size_t)c1 * 64 + lane] +
           w2 * Z[(size_t)c2 * 64 + lane] + w3 * Z[(size_t)c3 * 64 + lane];
  }
  for (; e < cnt; e++) {
    int c = cr[e];
    acc += dinv[c] * Z[(size_t)c * 64 + lane];
  }
  float h2 = (lane < 40) ? fmaxf(acc * di, 0.0f) : -INFINITY;
  float m = h2;
  for (int off = 32; off > 0; off >>= 1) m = fmaxf(m, __shfl_xor(m, off, 64));
  float ex = (lane < 40) ? expf(h2 - m) : 0.0f;
  float s = ex;
  for (int off = 32; off > 0; off >>= 1) s += __shfl_xor(s, off, 64);
  float ls = logf(s);
  if (lane < 40) out[(size_t)row * 40 + lane] = h2 - m - ls;
}

// ---------------------------------------------------------------------------
// Workspace (bytes, 16B-aligned):
//   cols @ 0 : 2097152        rowcount @ 2097152 : 32768
//   dinv @ 2129920 : 32768    diagv    @ 2162688 : 32768
//   XW1  @ 2195456 : 8388608  H        @ 10584064 : 8388608
//   HW2  @ 18972672 : 2097152 (8192 x 64, cols 40..63 zero)
//   Ah   @ 21069824 : 8388608 Al @ 29458432 : 8388608
//   Bh   @ 37847040 : 262144  Bl @ 38109184 : 262144   (end ~38.4 MB)
// ---------------------------------------------------------------------------
extern "C" void kernel_launch(void* const* d_in, const int* in_sizes, int n_in,
                              void* d_out, int out_size, void* d_ws, size_t ws_size,
                              hipStream_t stream) {
  (void)in_sizes; (void)n_in; (void)out_size; (void)ws_size;
  const float* x   = (const float*)d_in[0];
  const float* adj = (const float*)d_in[1];
  const float* W1  = (const float*)d_in[2];
  const float* W2  = (const float*)d_in[3];
  float* out = (float*)d_out;
  char* ws = (char*)d_ws;

  int*   cols     = (int*)(ws);
  int*   rowcount = (int*)(ws + 2097152);
  float* dinv     = (float*)(ws + 2129920);
  float* diagv    = (float*)(ws + 2162688);
  float* XW1      = (float*)(ws + 2195456);
  float* H        = (float*)(ws + 10584064);
  float* HW2      = (float*)(ws + 18972672);
  unsigned short* Ah = (unsigned short*)(ws + 21069824);
  unsigned short* Al = (unsigned short*)(ws + 29458432);
  unsigned short* Bh = (unsigned short*)(ws + 37847040);
  unsigned short* Bl = (unsigned short*)(ws + 38109184);

  hipLaunchKernelGGL(build_graph, dim3(NV), dim3(256), 0, stream,
                     adj, cols, rowcount, dinv, diagv);
  hipLaunchKernelGGL(split_a, dim3(NV * 512 / 4 / 256), dim3(256), 0, stream,
                     x, Ah, Al);
  hipLaunchKernelGGL(split_w1t, dim3(256, 2), dim3(256), 0, stream,
                     W1, Bh, Bl);
  hipLaunchKernelGGL(gemm1_mfma, dim3(4, 64), dim3(256), 0, stream,
                     Ah, Al, Bh, Bl, XW1);
  hipLaunchKernelGGL(spmm_relu_k, dim3(NV / 4), dim3(256), 0, stream,
                     XW1, cols, rowcount, dinv, diagv, H);
  hipLaunchKernelGGL(gemm_f32, dim3(1, 128), dim3(256), 0, stream,
                     H, W2, HW2, NV, 256, 40, 40, 64);
  hipLaunchKernelGGL(spmm2_lsm_k, dim3(NV / 4), dim3(256), 0, stream,
                     HW2, cols, rowcount, dinv, diagv, out);
}

// Round 4
// 433.953 us; speedup vs baseline: 1.0916x; 1.0090x over previous
//
#include <hip/hip_runtime.h>
#include <math.h>

#define NV 8192
#define CAP 64

typedef __attribute__((ext_vector_type(8))) short short8;
typedef __attribute__((ext_vector_type(4))) float f32x4;

static __device__ __forceinline__ unsigned short f2bf(float v) {
  unsigned int u = __float_as_uint(v);
  unsigned int r = (u + 0x7fffu + ((u >> 16) & 1u)) >> 16;  // RNE
  return (unsigned short)r;
}
static __device__ __forceinline__ float bf2f(unsigned short h) {
  return __uint_as_float(((unsigned int)h) << 16);
}

// ---------------------------------------------------------------------------
// MEGA kernel: blocks 0..255 = GEMM1 (XW1 = x @ W1, split-bf16 MFMA, inline
// f32->hi/lo conversion during staging); blocks 256..8447 = build_graph
// (one pass over adj: ELL cols, popcount degree, diag flag).
// The two paths are data-independent; GEMM1 (compute-bound) overlaps
// build (HBM-bound, ~42 us floor). Combined LDS ~31 KB -> build keeps
// ~4 blocks/CU for BW. Low blockIdx dispatches first -> gemm starts early.
// ---------------------------------------------------------------------------
__global__ __launch_bounds__(256) void mega_build_gemm1(
    const float* __restrict__ adj, const float* __restrict__ x,
    const float* __restrict__ W1, int* __restrict__ cols,
    int* __restrict__ rowcount, float* __restrict__ dinv,
    float* __restrict__ diagv, float* __restrict__ XW1) {
  // --- shared (union of both paths; total ~31 KB) ---
  __shared__ __align__(16) unsigned short sAh[128][40];
  __shared__ __align__(16) unsigned short sAl[128][40];
  __shared__ __align__(16) unsigned short sBh[64][40];
  __shared__ __align__(16) unsigned short sBl[64][40];
  __shared__ int cnt;
  __shared__ int diag_nz;
  __shared__ int wsum[4];

  int t = threadIdx.x;
  int lane = t & 63;

  if (blockIdx.x < 256) {
    // ===================== GEMM1 path =====================
    const int K = 512;
    int b = blockIdx.x;
    int bn = (b & 3) * 64;
    int bm = (b >> 2) * 128;
    int w = t >> 6;
    int quad = lane >> 4, m16 = lane & 15;
    f32x4 acc[2][4] = {};
    for (int k0 = 0; k0 < K; k0 += 32) {
      // A tile: 128 rows x 32 k, from x (f32) with inline hi/lo split.
#pragma unroll
      for (int i = 0; i < 4; i++) {
        int id = t + i * 256;        // 1024 float4 slots
        int row = id >> 3;           // 0..127
        int fq = id & 7;             // float4 index in row (k = fq*4)
        float4 v = *(const float4*)&x[(size_t)(bm + row) * K + k0 + fq * 4];
        ushort4 h, l;
        h.x = f2bf(v.x); l.x = f2bf(v.x - bf2f(h.x));
        h.y = f2bf(v.y); l.y = f2bf(v.y - bf2f(h.y));
        h.z = f2bf(v.z); l.z = f2bf(v.z - bf2f(h.z));
        h.w = f2bf(v.w); l.w = f2bf(v.w - bf2f(h.w));
        *(ushort4*)&sAh[row][fq * 4] = h;
        *(ushort4*)&sAl[row][fq * 4] = l;
      }
      // B tile: 64 n x 32 k, transposed from W1[k][n] (f32, coalesced in n),
      // scatter b16 writes into [n][k] layout.
#pragma unroll
      for (int j = 0; j < 2; j++) {
        int id = t + j * 256;        // 512 float4 slots
        int k = id >> 4;             // 0..31
        int n4 = (id & 15) * 4;      // 0..60
        float4 v = *(const float4*)&W1[(size_t)(k0 + k) * 256 + bn + n4];
        float va[4] = {v.x, v.y, v.z, v.w};
#pragma unroll
        for (int c = 0; c < 4; c++) {
          unsigned short h = f2bf(va[c]);
          sBh[n4 + c][k] = h;
          sBl[n4 + c][k] = f2bf(va[c] - bf2f(h));
        }
      }
      __syncthreads();
      short8 ah[2], al[2], bh[4], bl[4];
#pragma unroll
      for (int i = 0; i < 2; i++) {
        ah[i] = *(const short8*)&sAh[w * 32 + i * 16 + m16][quad * 8];
        al[i] = *(const short8*)&sAl[w * 32 + i * 16 + m16][quad * 8];
      }
#pragma unroll
      for (int j = 0; j < 4; j++) {
        bh[j] = *(const short8*)&sBh[j * 16 + m16][quad * 8];
        bl[j] = *(const short8*)&sBl[j * 16 + m16][quad * 8];
      }
#pragma unroll
      for (int i = 0; i < 2; i++)
#pragma unroll
        for (int j = 0; j < 4; j++) {
          acc[i][j] = __builtin_amdgcn_mfma_f32_16x16x32_bf16(ah[i], bh[j], acc[i][j], 0, 0, 0);
          acc[i][j] = __builtin_amdgcn_mfma_f32_16x16x32_bf16(al[i], bh[j], acc[i][j], 0, 0, 0);
          acc[i][j] = __builtin_amdgcn_mfma_f32_16x16x32_bf16(ah[i], bl[j], acc[i][j], 0, 0, 0);
        }
      __syncthreads();
    }
#pragma unroll
    for (int i = 0; i < 2; i++)
#pragma unroll
      for (int j = 0; j < 4; j++)
#pragma unroll
        for (int r = 0; r < 4; r++)
          XW1[(size_t)(bm + w * 32 + i * 16 + quad * 4 + r) * 256 + bn + j * 16 + m16] =
              acc[i][j][r];
  } else {
    // ===================== build_graph path =====================
    int row = blockIdx.x - 256;
    if (t == 0) { cnt = 0; diag_nz = 0; }
    __syncthreads();
    const float4* arow = (const float4*)(adj + (size_t)row * NV);
    int mycount = 0;
    for (int i = t; i < NV / 4; i += 256) {
      float4 v = arow[i];
      float va[4] = {v.x, v.y, v.z, v.w};
#pragma unroll
      for (int j = 0; j < 4; j++) {
        bool nz = (va[j] != 0.0f);
        mycount += nz ? 1 : 0;
        int c = i * 4 + j;
        bool isdiag = nz && (c == row);
        bool take = nz && !isdiag;
        if (isdiag) diag_nz = 1;
        unsigned long long m = __ballot(take);
        if (m != 0ull) {
          int tot = __popcll(m);
          int pre = __popcll(m & ((1ull << lane) - 1ull));
          int leader = __ffsll((unsigned long long)m) - 1;
          int base = 0;
          if (lane == leader) base = atomicAdd(&cnt, tot);
          base = __shfl(base, leader, 64);
          if (take) {
            int p = base + pre;
            if (p < CAP) cols[(size_t)row * CAP + p] = c;
          }
        }
      }
    }
    for (int off = 32; off > 0; off >>= 1) mycount += __shfl_xor(mycount, off, 64);
    if (lane == 0) wsum[t >> 6] = mycount;
    __syncthreads();
    if (t == 0) {
      int nnz = wsum[0] + wsum[1] + wsum[2] + wsum[3];
      float deg = (float)nnz + 1.0f;
      dinv[row] = 1.0f / sqrtf(deg);
      diagv[row] = diag_nz ? 2.0f : 1.0f;
      rowcount[row] = cnt > CAP ? CAP : cnt;
    }
  }
}

// ---------------------------------------------------------------------------
// Kernel D: f32 GEMM for layer 2 (167 MFLOP): C = A[M x K] @ B[K x Nvalid],
// 64x64 tile, 4x4 micro-tile; cols >= Nvalid zero-padded (N=40 -> 64).
// ---------------------------------------------------------------------------
__global__ __launch_bounds__(256) void gemm_f32(
    const float* __restrict__ A, const float* __restrict__ B,
    float* __restrict__ C, int M, int K, int Nvalid, int ldb, int ldc) {
  __shared__ float As[16][68];
  __shared__ float Bs[16][64];
  int t = threadIdx.x;
  int bm0 = blockIdx.y * 64;
  int bn0 = blockIdx.x * 64;
  int tx = t & 15, ty = t >> 4;
  int ar = t >> 2;
  int ak = (t & 3) * 4;
  int bk = t >> 4;
  int bn = (t & 15) * 4;
  float acc[4][4] = {};
  for (int k0 = 0; k0 < K; k0 += 16) {
    float4 av = *(const float4*)(A + (size_t)(bm0 + ar) * K + k0 + ak);
    float4 bv;
    int bc = bn0 + bn;
    if (bc + 3 < Nvalid) {
      bv = *(const float4*)(B + (size_t)(k0 + bk) * ldb + bc);
    } else {
      bv.x = (bc + 0 < Nvalid) ? B[(size_t)(k0 + bk) * ldb + bc + 0] : 0.0f;
      bv.y = (bc + 1 < Nvalid) ? B[(size_t)(k0 + bk) * ldb + bc + 1] : 0.0f;
      bv.z = (bc + 2 < Nvalid) ? B[(size_t)(k0 + bk) * ldb + bc + 2] : 0.0f;
      bv.w = (bc + 3 < Nvalid) ? B[(size_t)(k0 + bk) * ldb + bc + 3] : 0.0f;
    }
    As[ak + 0][ar] = av.x;
    As[ak + 1][ar] = av.y;
    As[ak + 2][ar] = av.z;
    As[ak + 3][ar] = av.w;
    *(float4*)(&Bs[bk][bn]) = bv;
    __syncthreads();
#pragma unroll
    for (int kk = 0; kk < 16; kk++) {
      float4 a = *(const float4*)(&As[kk][ty * 4]);
      float4 b = *(const float4*)(&Bs[kk][tx * 4]);
      acc[0][0] += a.x * b.x; acc[0][1] += a.x * b.y; acc[0][2] += a.x * b.z; acc[0][3] += a.x * b.w;
      acc[1][0] += a.y * b.x; acc[1][1] += a.y * b.y; acc[1][2] += a.y * b.z; acc[1][3] += a.y * b.w;
      acc[2][0] += a.z * b.x; acc[2][1] += a.z * b.y; acc[2][2] += a.z * b.z; acc[2][3] += a.z * b.w;
      acc[3][0] += a.w * b.x; acc[3][1] += a.w * b.y; acc[3][2] += a.w * b.z; acc[3][3] += a.w * b.w;
    }
    __syncthreads();
  }
#pragma unroll
  for (int i = 0; i < 4; i++) {
    *(float4*)(C + (size_t)(bm0 + ty * 4 + i) * ldc + bn0 + tx * 4) =
        make_float4(acc[i][0], acc[i][1], acc[i][2], acc[i][3]);
  }
}

// ---------------------------------------------------------------------------
// Kernel C: layer-1 aggregate + relu. One WAVE per row, float4 per lane,
// unroll x4 -> 4 independent 1 KB gathers in flight.
// ---------------------------------------------------------------------------
__global__ __launch_bounds__(256) void spmm_relu_k(
    const float* __restrict__ Z, const int* __restrict__ cols,
    const int* __restrict__ rowcount, const float* __restrict__ dinv,
    const float* __restrict__ diagv, float* __restrict__ H) {
  int lane = threadIdx.x & 63;
  int row = blockIdx.x * 4 + (threadIdx.x >> 6);
  const float4* Zr = (const float4*)Z;
  float di = dinv[row];
  float4 z = Zr[(size_t)row * 64 + lane];
  float dd = diagv[row] * di;
  float4 acc;
  acc.x = dd * z.x; acc.y = dd * z.y; acc.z = dd * z.z; acc.w = dd * z.w;
  int cnt = rowcount[row];
  const int* cr = cols + (size_t)row * CAP;
  int e = 0;
  for (; e + 4 <= cnt; e += 4) {
    int c0 = cr[e + 0], c1 = cr[e + 1], c2 = cr[e + 2], c3 = cr[e + 3];
    float w0 = dinv[c0], w1 = dinv[c1], w2 = dinv[c2], w3 = dinv[c3];
    float4 g0 = Zr[(size_t)c0 * 64 + lane];
    float4 g1 = Zr[(size_t)c1 * 64 + lane];
    float4 g2 = Zr[(size_t)c2 * 64 + lane];
    float4 g3 = Zr[(size_t)c3 * 64 + lane];
    acc.x += w0 * g0.x + w1 * g1.x + w2 * g2.x + w3 * g3.x;
    acc.y += w0 * g0.y + w1 * g1.y + w2 * g2.y + w3 * g3.y;
    acc.z += w0 * g0.z + w1 * g1.z + w2 * g2.z + w3 * g3.z;
    acc.w += w0 * g0.w + w1 * g1.w + w2 * g2.w + w3 * g3.w;
  }
  for (; e < cnt; e++) {
    int c = cr[e];
    float w = dinv[c];
    float4 g = Zr[(size_t)c * 64 + lane];
    acc.x += w * g.x; acc.y += w * g.y; acc.z += w * g.z; acc.w += w * g.w;
  }
  float4 o;
  o.x = fmaxf(acc.x * di, 0.0f);
  o.y = fmaxf(acc.y * di, 0.0f);
  o.z = fmaxf(acc.z * di, 0.0f);
  o.w = fmaxf(acc.w * di, 0.0f);
  ((float4*)H)[(size_t)row * 64 + lane] = o;
}

// ---------------------------------------------------------------------------
// Kernel E: layer-2 aggregate + relu + log_softmax (wave per row, 64-wide
// padded HW2; pad lanes masked via -INF so pad garbage never matters).
// ---------------------------------------------------------------------------
__global__ __launch_bounds__(256) void spmm2_lsm_k(
    const float* __restrict__ Z, const int* __restrict__ cols,
    const int* __restrict__ rowcount, const float* __restrict__ dinv,
    const float* __restrict__ diagv, float* __restrict__ out) {
  int lane = threadIdx.x & 63;
  int row = blockIdx.x * 4 + (threadIdx.x >> 6);
  float di = dinv[row];
  float acc = diagv[row] * di * Z[(size_t)row * 64 + lane];
  int cnt = rowcount[row];
  const int* cr = cols + (size_t)row * CAP;
  int e = 0;
  for (; e + 4 <= cnt; e += 4) {
    int c0 = cr[e + 0], c1 = cr[e + 1], c2 = cr[e + 2], c3 = cr[e + 3];
    float w0 = dinv[c0], w1 = dinv[c1], w2 = dinv[c2], w3 = dinv[c3];
    acc += w0 * Z[(size_t)c0 * 64 + lane] + w1 * Z[(size_t)c1 * 64 + lane] +
           w2 * Z[(size_t)c2 * 64 + lane] + w3 * Z[(size_t)c3 * 64 + lane];
  }
  for (; e < cnt; e++) {
    int c = cr[e];
    acc += dinv[c] * Z[(size_t)c * 64 + lane];
  }
  float h2 = (lane < 40) ? fmaxf(acc * di, 0.0f) : -INFINITY;
  float m = h2;
  for (int off = 32; off > 0; off >>= 1) m = fmaxf(m, __shfl_xor(m, off, 64));
  float ex = (lane < 40) ? expf(h2 - m) : 0.0f;
  float s = ex;
  for (int off = 32; off > 0; off >>= 1) s += __shfl_xor(s, off, 64);
  float ls = logf(s);
  if (lane < 40) out[(size_t)row * 40 + lane] = h2 - m - ls;
}

// ---------------------------------------------------------------------------
// Workspace (bytes, 16B-aligned):
//   cols @ 0 : 2097152        rowcount @ 2097152 : 32768
//   dinv @ 2129920 : 32768    diagv    @ 2162688 : 32768
//   XW1  @ 2195456 : 8388608  H        @ 10584064 : 8388608
//   HW2  @ 18972672 : 2097152 (8192 x 64, cols 40..63 zero-padded by gemm_f32)
// ---------------------------------------------------------------------------
extern "C" void kernel_launch(void* const* d_in, const int* in_sizes, int n_in,
                              void* d_out, int out_size, void* d_ws, size_t ws_size,
                              hipStream_t stream) {
  (void)in_sizes; (void)n_in; (void)out_size; (void)ws_size;
  const float* x   = (const float*)d_in[0];
  const float* adj = (const float*)d_in[1];
  const float* W1  = (const float*)d_in[2];
  const float* W2  = (const float*)d_in[3];
  float* out = (float*)d_out;
  char* ws = (char*)d_ws;

  int*   cols     = (int*)(ws);
  int*   rowcount = (int*)(ws + 2097152);
  float* dinv     = (float*)(ws + 2129920);
  float* diagv    = (float*)(ws + 2162688);
  float* XW1      = (float*)(ws + 2195456);
  float* H        = (float*)(ws + 10584064);
  float* HW2      = (float*)(ws + 18972672);

  hipLaunchKernelGGL(mega_build_gemm1, dim3(256 + NV), dim3(256), 0, stream,
                     adj, x, W1, cols, rowcount, dinv, diagv, XW1);
  hipLaunchKernelGGL(spmm_relu_k, dim3(NV / 4), dim3(256), 0, stream,
                     XW1, cols, rowcount, dinv, diagv, H);
  hipLaunchKernelGGL(gemm_f32, dim3(1, 128), dim3(256), 0, stream,
                     H, W2, HW2, NV, 256, 40, 40, 64);
  hipLaunchKernelGGL(spmm2_lsm_k, dim3(NV / 4), dim3(256), 0, stream,
                     HW2, cols, rowcount, dinv, diagv, out);
}

// Round 5
// 431.370 us; speedup vs baseline: 1.0982x; 1.0060x over previous
//
#include <hip/hip_runtime.h>
#include <math.h>

#define NV 8192
#define CAP 64

typedef __attribute__((ext_vector_type(8))) short short8;
typedef __attribute__((ext_vector_type(4))) float f32x4;

static __device__ __forceinline__ unsigned short f2bf(float v) {
  unsigned int u = __float_as_uint(v);
  unsigned int r = (u + 0x7fffu + ((u >> 16) & 1u)) >> 16;  // RNE
  return (unsigned short)r;
}
static __device__ __forceinline__ float bf2f(unsigned short h) {
  return __uint_as_float(((unsigned int)h) << 16);
}

// ---------------------------------------------------------------------------
// MEGA kernel: blocks 0..255 = GEMM1 (XW1 = x @ W1, split-bf16 MFMA, inline
// f32->hi/lo conversion during staging); blocks 256..8447 = build_graph
// (one pass over adj: ELL cols, popcount degree, diag flag).
// Data-independent paths; GEMM1 (compute) rides under build's ~45 us HBM
// shadow (m114: MFMA/VALU waves co-schedule). Combined LDS ~31 KB.
// ---------------------------------------------------------------------------
__global__ __launch_bounds__(256) void mega_build_gemm1(
    const float* __restrict__ adj, const float* __restrict__ x,
    const float* __restrict__ W1, int* __restrict__ cols,
    int* __restrict__ rowcount, float* __restrict__ dinv,
    float* __restrict__ diagv, float* __restrict__ XW1) {
  __shared__ __align__(16) unsigned short sAh[128][40];
  __shared__ __align__(16) unsigned short sAl[128][40];
  __shared__ __align__(16) unsigned short sBh[64][40];
  __shared__ __align__(16) unsigned short sBl[64][40];
  __shared__ int cnt;
  __shared__ int diag_nz;
  __shared__ int wsum[4];

  int t = threadIdx.x;
  int lane = t & 63;

  if (blockIdx.x < 256) {
    // ===================== GEMM1 path =====================
    const int K = 512;
    int b = blockIdx.x;
    int bn = (b & 3) * 64;
    int bm = (b >> 2) * 128;
    int w = t >> 6;
    int quad = lane >> 4, m16 = lane & 15;
    f32x4 acc[2][4] = {};
    for (int k0 = 0; k0 < K; k0 += 32) {
#pragma unroll
      for (int i = 0; i < 4; i++) {
        int id = t + i * 256;
        int row = id >> 3;
        int fq = id & 7;
        float4 v = *(const float4*)&x[(size_t)(bm + row) * K + k0 + fq * 4];
        ushort4 h, l;
        h.x = f2bf(v.x); l.x = f2bf(v.x - bf2f(h.x));
        h.y = f2bf(v.y); l.y = f2bf(v.y - bf2f(h.y));
        h.z = f2bf(v.z); l.z = f2bf(v.z - bf2f(h.z));
        h.w = f2bf(v.w); l.w = f2bf(v.w - bf2f(h.w));
        *(ushort4*)&sAh[row][fq * 4] = h;
        *(ushort4*)&sAl[row][fq * 4] = l;
      }
#pragma unroll
      for (int j = 0; j < 2; j++) {
        int id = t + j * 256;
        int k = id >> 4;
        int n4 = (id & 15) * 4;
        float4 v = *(const float4*)&W1[(size_t)(k0 + k) * 256 + bn + n4];
        float va[4] = {v.x, v.y, v.z, v.w};
#pragma unroll
        for (int c = 0; c < 4; c++) {
          unsigned short h = f2bf(va[c]);
          sBh[n4 + c][k] = h;
          sBl[n4 + c][k] = f2bf(va[c] - bf2f(h));
        }
      }
      __syncthreads();
      short8 ah[2], al[2], bh[4], bl[4];
#pragma unroll
      for (int i = 0; i < 2; i++) {
        ah[i] = *(const short8*)&sAh[w * 32 + i * 16 + m16][quad * 8];
        al[i] = *(const short8*)&sAl[w * 32 + i * 16 + m16][quad * 8];
      }
#pragma unroll
      for (int j = 0; j < 4; j++) {
        bh[j] = *(const short8*)&sBh[j * 16 + m16][quad * 8];
        bl[j] = *(const short8*)&sBl[j * 16 + m16][quad * 8];
      }
#pragma unroll
      for (int i = 0; i < 2; i++)
#pragma unroll
        for (int j = 0; j < 4; j++) {
          acc[i][j] = __builtin_amdgcn_mfma_f32_16x16x32_bf16(ah[i], bh[j], acc[i][j], 0, 0, 0);
          acc[i][j] = __builtin_amdgcn_mfma_f32_16x16x32_bf16(al[i], bh[j], acc[i][j], 0, 0, 0);
          acc[i][j] = __builtin_amdgcn_mfma_f32_16x16x32_bf16(ah[i], bl[j], acc[i][j], 0, 0, 0);
        }
      __syncthreads();
    }
#pragma unroll
    for (int i = 0; i < 2; i++)
#pragma unroll
      for (int j = 0; j < 4; j++)
#pragma unroll
        for (int r = 0; r < 4; r++)
          XW1[(size_t)(bm + w * 32 + i * 16 + quad * 4 + r) * 256 + bn + j * 16 + m16] =
              acc[i][j][r];
  } else {
    // ===================== build_graph path =====================
    int row = blockIdx.x - 256;
    if (t == 0) { cnt = 0; diag_nz = 0; }
    __syncthreads();
    const float4* arow = (const float4*)(adj + (size_t)row * NV);
    int mycount = 0;
    for (int i = t; i < NV / 4; i += 256) {
      float4 v = arow[i];
      float va[4] = {v.x, v.y, v.z, v.w};
#pragma unroll
      for (int j = 0; j < 4; j++) {
        bool nz = (va[j] != 0.0f);
        mycount += nz ? 1 : 0;
        int c = i * 4 + j;
        bool isdiag = nz && (c == row);
        bool take = nz && !isdiag;
        if (isdiag) diag_nz = 1;
        unsigned long long m = __ballot(take);
        if (m != 0ull) {
          int tot = __popcll(m);
          int pre = __popcll(m & ((1ull << lane) - 1ull));
          int leader = __ffsll((unsigned long long)m) - 1;
          int base = 0;
          if (lane == leader) base = atomicAdd(&cnt, tot);
          base = __shfl(base, leader, 64);
          if (take) {
            int p = base + pre;
            if (p < CAP) cols[(size_t)row * CAP + p] = c;
          }
        }
      }
    }
    for (int off = 32; off > 0; off >>= 1) mycount += __shfl_xor(mycount, off, 64);
    if (lane == 0) wsum[t >> 6] = mycount;
    __syncthreads();
    if (t == 0) {
      int nnz = wsum[0] + wsum[1] + wsum[2] + wsum[3];
      float deg = (float)nnz + 1.0f;
      dinv[row] = 1.0f / sqrtf(deg);
      diagv[row] = diag_nz ? 2.0f : 1.0f;
      rowcount[row] = cnt > CAP ? CAP : cnt;
    }
  }
}

// ---------------------------------------------------------------------------
// Kernel C: layer-1 aggregate + relu. One WAVE per row, float4 per lane,
// unroll x4 -> 4 independent 1 KB gathers in flight.
// ---------------------------------------------------------------------------
__global__ __launch_bounds__(256) void spmm_relu_k(
    const float* __restrict__ Z, const int* __restrict__ cols,
    const int* __restrict__ rowcount, const float* __restrict__ dinv,
    const float* __restrict__ diagv, float* __restrict__ H) {
  int lane = threadIdx.x & 63;
  int row = blockIdx.x * 4 + (threadIdx.x >> 6);
  const float4* Zr = (const float4*)Z;
  float di = dinv[row];
  float4 z = Zr[(size_t)row * 64 + lane];
  float dd = diagv[row] * di;
  float4 acc;
  acc.x = dd * z.x; acc.y = dd * z.y; acc.z = dd * z.z; acc.w = dd * z.w;
  int cnt = rowcount[row];
  const int* cr = cols + (size_t)row * CAP;
  int e = 0;
  for (; e + 4 <= cnt; e += 4) {
    int c0 = cr[e + 0], c1 = cr[e + 1], c2 = cr[e + 2], c3 = cr[e + 3];
    float w0 = dinv[c0], w1 = dinv[c1], w2 = dinv[c2], w3 = dinv[c3];
    float4 g0 = Zr[(size_t)c0 * 64 + lane];
    float4 g1 = Zr[(size_t)c1 * 64 + lane];
    float4 g2 = Zr[(size_t)c2 * 64 + lane];
    float4 g3 = Zr[(size_t)c3 * 64 + lane];
    acc.x += w0 * g0.x + w1 * g1.x + w2 * g2.x + w3 * g3.x;
    acc.y += w0 * g0.y + w1 * g1.y + w2 * g2.y + w3 * g3.y;
    acc.z += w0 * g0.z + w1 * g1.z + w2 * g2.z + w3 * g3.z;
    acc.w += w0 * g0.w + w1 * g1.w + w2 * g2.w + w3 * g3.w;
  }
  for (; e < cnt; e++) {
    int c = cr[e];
    float w = dinv[c];
    float4 g = Zr[(size_t)c * 64 + lane];
    acc.x += w * g.x; acc.y += w * g.y; acc.z += w * g.z; acc.w += w * g.w;
  }
  float4 o;
  o.x = fmaxf(acc.x * di, 0.0f);
  o.y = fmaxf(acc.y * di, 0.0f);
  o.z = fmaxf(acc.z * di, 0.0f);
  o.w = fmaxf(acc.w * di, 0.0f);
  ((float4*)H)[(size_t)row * 64 + lane] = o;
}

// ---------------------------------------------------------------------------
// Kernel D: layer-2 GEMM via split-bf16 MFMA. HW2[8192][64] = H @ W2 with
// cols 40..63 exact zeros (B staged as zero there). 256 blocks x 32-row
// tiles (vs 128-block f32 VALU before -> full GPU + matrix pipe).
// Wave w: m-half = w&1 (16 rows), n-pair = (w>>1)*2 (2x 16-col frags).
// LDS ~15.4 KB.
// ---------------------------------------------------------------------------
__global__ __launch_bounds__(256) void gemm2_mfma(
    const float* __restrict__ H, const float* __restrict__ W2,
    float* __restrict__ HW2) {
  const int K = 256;
  __shared__ __align__(16) unsigned short sAh[32][40];
  __shared__ __align__(16) unsigned short sAl[32][40];
  __shared__ __align__(16) unsigned short sBh[64][40];
  __shared__ __align__(16) unsigned short sBl[64][40];
  int t = threadIdx.x;
  int bm = blockIdx.x * 32;
  int lane = t & 63, w = t >> 6;
  int quad = lane >> 4, m16 = lane & 15;
  int i = w & 1;          // m-half
  int jj = (w >> 1) * 2;  // first n-frag
  f32x4 acc[2] = {};
  for (int k0 = 0; k0 < K; k0 += 32) {
    {  // A tile: 32 rows x 32 k from H (f32), inline hi/lo split
      int row = t >> 3;        // 0..31
      int fq = t & 7;          // k = fq*4
      float4 v = *(const float4*)&H[(size_t)(bm + row) * K + k0 + fq * 4];
      ushort4 h, l;
      h.x = f2bf(v.x); l.x = f2bf(v.x - bf2f(h.x));
      h.y = f2bf(v.y); l.y = f2bf(v.y - bf2f(h.y));
      h.z = f2bf(v.z); l.z = f2bf(v.z - bf2f(h.z));
      h.w = f2bf(v.w); l.w = f2bf(v.w - bf2f(h.w));
      *(ushort4*)&sAh[row][fq * 4] = h;
      *(ushort4*)&sAl[row][fq * 4] = l;
    }
#pragma unroll
    for (int j = 0; j < 2; j++) {  // B tile: 64 n x 32 k from W2[k][n<40]
      int id = t + j * 256;        // 0..511
      int k = id >> 4;             // 0..31
      int n4 = (id & 15) * 4;      // 0..60
#pragma unroll
      for (int c = 0; c < 4; c++) {
        float v = (n4 + c < 40) ? W2[(size_t)(k0 + k) * 40 + n4 + c] : 0.0f;
        unsigned short h = f2bf(v);
        sBh[n4 + c][k] = h;
        sBl[n4 + c][k] = f2bf(v - bf2f(h));
      }
    }
    __syncthreads();
    short8 ah = *(const short8*)&sAh[i * 16 + m16][quad * 8];
    short8 al = *(const short8*)&sAl[i * 16 + m16][quad * 8];
#pragma unroll
    for (int jx = 0; jx < 2; jx++) {
      short8 bh = *(const short8*)&sBh[(jj + jx) * 16 + m16][quad * 8];
      short8 bl = *(const short8*)&sBl[(jj + jx) * 16 + m16][quad * 8];
      acc[jx] = __builtin_amdgcn_mfma_f32_16x16x32_bf16(ah, bh, acc[jx], 0, 0, 0);
      acc[jx] = __builtin_amdgcn_mfma_f32_16x16x32_bf16(al, bh, acc[jx], 0, 0, 0);
      acc[jx] = __builtin_amdgcn_mfma_f32_16x16x32_bf16(ah, bl, acc[jx], 0, 0, 0);
    }
    __syncthreads();
  }
#pragma unroll
  for (int jx = 0; jx < 2; jx++)
#pragma unroll
    for (int r = 0; r < 4; r++)
      HW2[(size_t)(bm + i * 16 + quad * 4 + r) * 64 + (jj + jx) * 16 + m16] =
          acc[jx][r];
}

// ---------------------------------------------------------------------------
// Kernel E: layer-2 aggregate + relu + log_softmax (wave per row, 64-wide
// padded HW2; cols 40..63 exact zeros from gemm2_mfma).
// ---------------------------------------------------------------------------
__global__ __launch_bounds__(256) void spmm2_lsm_k(
    const float* __restrict__ Z, const int* __restrict__ cols,
    const int* __restrict__ rowcount, const float* __restrict__ dinv,
    const float* __restrict__ diagv, float* __restrict__ out) {
  int lane = threadIdx.x & 63;
  int row = blockIdx.x * 4 + (threadIdx.x >> 6);
  float di = dinv[row];
  float acc = diagv[row] * di * Z[(size_t)row * 64 + lane];
  int cnt = rowcount[row];
  const int* cr = cols + (size_t)row * CAP;
  int e = 0;
  for (; e + 4 <= cnt; e += 4) {
    int c0 = cr[e + 0], c1 = cr[e + 1], c2 = cr[e + 2], c3 = cr[e + 3];
    float w0 = dinv[c0], w1 = dinv[c1], w2 = dinv[c2], w3 = dinv[c3];
    acc += w0 * Z[(size_t)c0 * 64 + lane] + w1 * Z[(size_t)c1 * 64 + lane] +
           w2 * Z[(size_t)c2 * 64 + lane] + w3 * Z[(size_t)c3 * 64 + lane];
  }
  for (; e < cnt; e++) {
    int c = cr[e];
    acc += dinv[c] * Z[(size_t)c * 64 + lane];
  }
  float h2 = (lane < 40) ? fmaxf(acc * di, 0.0f) : -INFINITY;
  float m = h2;
  for (int off = 32; off > 0; off >>= 1) m = fmaxf(m, __shfl_xor(m, off, 64));
  float ex = (lane < 40) ? expf(h2 - m) : 0.0f;
  float s = ex;
  for (int off = 32; off > 0; off >>= 1) s += __shfl_xor(s, off, 64);
  float ls = logf(s);
  if (lane < 40) out[(size_t)row * 40 + lane] = h2 - m - ls;
}

// ---------------------------------------------------------------------------
// Workspace (bytes, 16B-aligned):
//   cols @ 0 : 2097152        rowcount @ 2097152 : 32768
//   dinv @ 2129920 : 32768    diagv    @ 2162688 : 32768
//   XW1  @ 2195456 : 8388608  H        @ 10584064 : 8388608
//   HW2  @ 18972672 : 2097152 (8192 x 64, cols 40..63 zero)
// ---------------------------------------------------------------------------
extern "C" void kernel_launch(void* const* d_in, const int* in_sizes, int n_in,
                              void* d_out, int out_size, void* d_ws, size_t ws_size,
                              hipStream_t stream) {
  (void)in_sizes; (void)n_in; (void)out_size; (void)ws_size;
  const float* x   = (const float*)d_in[0];
  const float* adj = (const float*)d_in[1];
  const float* W1  = (const float*)d_in[2];
  const float* W2  = (const float*)d_in[3];
  float* out = (float*)d_out;
  char* ws = (char*)d_ws;

  int*   cols     = (int*)(ws);
  int*   rowcount = (int*)(ws + 2097152);
  float* dinv     = (float*)(ws + 2129920);
  float* diagv    = (float*)(ws + 2162688);
  float* XW1      = (float*)(ws + 2195456);
  float* H        = (float*)(ws + 10584064);
  float* HW2      = (float*)(ws + 18972672);

  hipLaunchKernelGGL(mega_build_gemm1, dim3(256 + NV), dim3(256), 0, stream,
                     adj, x, W1, cols, rowcount, dinv, diagv, XW1);
  hipLaunchKernelGGL(spmm_relu_k, dim3(NV / 4), dim3(256), 0, stream,
                     XW1, cols, rowcount, dinv, diagv, H);
  hipLaunchKernelGGL(gemm2_mfma, dim3(NV / 32), dim3(256), 0, stream,
                     H, W2, HW2);
  hipLaunchKernelGGL(spmm2_lsm_k, dim3(NV / 4), dim3(256), 0, stream,
                     HW2, cols, rowcount, dinv, diagv, out);
}